// Round 7
// baseline (704.381 us; speedup 1.0000x reference)
//
#include <hip/hip_runtime.h>

// Problem constants: B=2, C=96, D=H=W=40, S=64000, NH=4, HD=24, L=40
// Exact simplifications vs reference:
//  - pos_attn branch dropped (softmax row-shift invariance)
//  - R6 rotations dropped (R orthogonal; (Rq).(Rk) = q.k; v unrotated)
//  - mod1@(lp2@B + b2) + b1 folded to W'@B + b'  (W' = mod1@lp2, exact)
// Round 7: conv3 v3 — weights in MFMA-fragment order [tap][mt][kc][lane][8]
// (contiguous staging, conflict-free ds_read_b128), register-prefetch double
// buffer, ONE barrier per tap. norm+gelu fused into consumer GEMM B-path.
// Stats finalize inline in GEMM prelude. All weight prep in one kernel.

typedef __attribute__((ext_vector_type(8))) _Float16 half8;
typedef __attribute__((ext_vector_type(2))) _Float16 half2;
typedef __attribute__((ext_vector_type(16))) float floatx16;

static __device__ __forceinline__ half2 h2(unsigned int u) {
    return __builtin_bit_cast(half2, u);
}
static __device__ __forceinline__ float fdot2(unsigned int a, unsigned int b, float c) {
    return __builtin_amdgcn_fdot2(h2(a), h2(b), c, false);
}

// ---------------- combined weight prep + zero ----------------
// ranges: [0,248832) wf frag-order | [248832,258048) wfold | [258048,267264) wm2
// | [267264,294912) wq | [294912,304128) wpj | [304128,304224) bfold | [304224,304992) raw zero
__global__ __launch_bounds__(256) void k_prep(const float* __restrict__ lp1_w,
                                              const float* __restrict__ lp2_w,
                                              const float* __restrict__ lp2_b,
                                              const float* __restrict__ mod1_w,
                                              const float* __restrict__ mod1_b,
                                              const float* __restrict__ mod2_w,
                                              const float* __restrict__ qkv_w,
                                              const float* __restrict__ proj_w,
                                              _Float16* __restrict__ wf,
                                              _Float16* __restrict__ wfold,
                                              _Float16* __restrict__ wm2,
                                              _Float16* __restrict__ wq,
                                              _Float16* __restrict__ wpj,
                                              float* __restrict__ bfold,
                                              float* __restrict__ raw) {
    int id = blockIdx.x * 256 + threadIdx.x;
    if (id < 248832) {
        int tap = id / 9216, r = id % 9216;
        int mt = r / 3072, r2 = r % 3072;
        int kc = r2 / 512, r3 = r2 % 512;
        int lane = r3 / 8, e = r3 % 8;
        int m = mt * 32 + (lane & 31);
        int c = kc * 16 + (lane >> 5) * 8 + e;
        wf[id] = (_Float16)lp1_w[(m * 96 + c) * 27 + tap];
    } else if (id < 258048) {
        int i = id - 248832;
        int o = i / 96, c = i % 96;
        float a = 0.f;
        for (int k = 0; k < 96; k++) a += mod1_w[o * 96 + k] * lp2_w[k * 96 + c];
        wfold[i] = (_Float16)a;
    } else if (id < 267264) {
        int i = id - 258048;
        wm2[i] = (_Float16)mod2_w[i];
    } else if (id < 294912) {
        int i = id - 267264;
        wq[i] = (_Float16)qkv_w[i];
    } else if (id < 304128) {
        int i = id - 294912;
        wpj[i] = (_Float16)proj_w[i];
    } else if (id < 304224) {
        int o = id - 304128;
        float a = mod1_b[o];
        for (int k = 0; k < 96; k++) a += mod1_w[o * 96 + k] * lp2_b[k];
        bfold[o] = a;
    } else if (id < 304992) {
        raw[id - 304224] = 0.f;
    }
}

// ---------------- prep: pos fp32 [b][c][s] -> f16 [b][s][c] ----------------
__global__ __launch_bounds__(256) void k_cvt_in(const float* __restrict__ pos,
                                                _Float16* __restrict__ in_t) {
    __shared__ _Float16 lds[64][97];
    int bid = blockIdx.x;
    int b = bid / 1000, s0 = (bid % 1000) * 64;
    int t = threadIdx.x;
    for (int i = t; i < 6144; i += 256) {
        int c = i / 64, sl = i % 64;
        lds[sl][c] = (_Float16)pos[(b * 96 + c) * 64000 + s0 + sl];
    }
    __syncthreads();
    _Float16* outp = in_t + ((size_t)b * 64000 + s0) * 96;
    for (int i = t; i < 6144; i += 256) {
        int sl = i / 96, c = i % 96;
        outp[i] = lds[sl][c];
    }
}

// ---------------- conv 3x3x3 circular: fragment-order LDS + reg-prefetch dbuf ----------------
// wf layout [tap][mt][kc][lane][8]: staging = straight copy; ds_read_b128 = lane-sequential.
// One __syncthreads per tap. Output f16 [b][s][96] via padded LDS transpose.
__global__ __launch_bounds__(256) void k_conv3_v3(const _Float16* __restrict__ in_t,
                                                  const _Float16* __restrict__ wf,
                                                  const float* __restrict__ bias,
                                                  _Float16* __restrict__ c3) {
    __shared__ __align__(16) char sm[74880];   // A0(18432) | A1(18432) | tbl(27648); epilogue st aliases from 0
    __shared__ float bsh[96];
    int* tbl = (int*)(sm + 36864);
    _Float16* st = (_Float16*)sm;              // 256 x 98 f16 = 50176 B (aliases A0/A1/part of tbl)
    int t = threadIdx.x;
    int bid = blockIdx.x;
    int b = bid / 250;
    int s0 = (bid % 250) * 256;

    for (int u = t; u < 27 * 256; u += 256) {
        int tap = u >> 8, nl = u & 255;
        int kd = tap / 9, kh = (tap / 3) % 3, kw = tap % 3;
        int s = s0 + nl;
        int d = s / 1600, r = s - d * 1600;
        int h = r / 40, w = r - h * 40;
        int ds = d + kd - 1; if (ds < 0) ds += 40; else if (ds >= 40) ds -= 40;
        int hs = h + kh - 1; if (hs < 0) hs += 40; else if (hs >= 40) hs -= 40;
        int wv2 = w + kw - 1; if (wv2 < 0) wv2 += 40; else if (wv2 >= 40) wv2 -= 40;
        tbl[u] = ((ds * 1600 + hs * 40 + wv2) * 96) * 2;   // byte offset in batch slab
    }
    if (t < 96) bsh[t] = bias[t];

    int wv = t >> 6, lane = t & 63;
    int n31 = lane & 31, kg = lane >> 5;
    const char* inb = (const char*)(in_t + (size_t)b * 64000 * 96) + kg * 16;
    const uint4* wsrc = (const uint4*)wf;      // 1152 uint4 per tap

    // prefetch tap 0 into registers
    uint4 pf[5];
#pragma unroll
    for (int k = 0; k < 5; k++) { int idx = t + k * 256; if (idx < 1152) pf[k] = wsrc[idx]; }
    __syncthreads();   // tbl ready
#pragma unroll
    for (int k = 0; k < 5; k++) { int idx = t + k * 256; if (idx < 1152) *(uint4*)(sm + idx * 16) = pf[k]; }

    floatx16 acc[3][2];
#pragma unroll
    for (int mt = 0; mt < 3; mt++)
#pragma unroll
        for (int nt = 0; nt < 2; nt++)
#pragma unroll
            for (int r = 0; r < 16; r++) acc[mt][nt][r] = 0.f;

    for (int tap = 0; tap < 27; tap++) {
        char* cur = sm + (tap & 1) * 18432;
        char* nxt = sm + ((tap + 1) & 1) * 18432;
        if (tap + 1 < 27) {
            const uint4* wn = wsrc + (tap + 1) * 1152;
#pragma unroll
            for (int k = 0; k < 5; k++) { int idx = t + k * 256; if (idx < 1152) pf[k] = wn[idx]; }
        }
        __syncthreads();   // A(tap) staged & visible; tap-1's reads of nxt complete
        int ta0 = tbl[tap * 256 + wv * 64 + n31];
        int ta1 = tbl[tap * 256 + wv * 64 + 32 + n31];
        const char* pb0 = inb + ta0;
        const char* pb1 = inb + ta1;
#pragma unroll
        for (int j = 0; j < 6; j++) {
            half8 a0 = *(half8*)(cur + 0 * 6144 + j * 1024 + lane * 16);
            half8 a1 = *(half8*)(cur + 1 * 6144 + j * 1024 + lane * 16);
            half8 a2 = *(half8*)(cur + 2 * 6144 + j * 1024 + lane * 16);
            half8 b0 = *(const half8*)(pb0 + j * 32);
            half8 b1 = *(const half8*)(pb1 + j * 32);
            acc[0][0] = __builtin_amdgcn_mfma_f32_32x32x16_f16(a0, b0, acc[0][0], 0, 0, 0);
            acc[0][1] = __builtin_amdgcn_mfma_f32_32x32x16_f16(a0, b1, acc[0][1], 0, 0, 0);
            acc[1][0] = __builtin_amdgcn_mfma_f32_32x32x16_f16(a1, b0, acc[1][0], 0, 0, 0);
            acc[1][1] = __builtin_amdgcn_mfma_f32_32x32x16_f16(a1, b1, acc[1][1], 0, 0, 0);
            acc[2][0] = __builtin_amdgcn_mfma_f32_32x32x16_f16(a2, b0, acc[2][0], 0, 0, 0);
            acc[2][1] = __builtin_amdgcn_mfma_f32_32x32x16_f16(a2, b1, acc[2][1], 0, 0, 0);
        }
        if (tap + 1 < 27) {
#pragma unroll
            for (int k = 0; k < 5; k++) { int idx = t + k * 256; if (idx < 1152) *(uint4*)(nxt + idx * 16) = pf[k]; }
        }
    }
    __syncthreads();   // all reads done; sm becomes epilogue staging

#pragma unroll
    for (int mt = 0; mt < 3; mt++)
#pragma unroll
        for (int nt = 0; nt < 2; nt++)
#pragma unroll
            for (int r = 0; r < 16; r++) {
                int m = mt * 32 + (r & 3) + 8 * (r >> 2) + 4 * kg;
                int sl = wv * 64 + nt * 32 + n31;
                st[sl * 98 + m] = (_Float16)(acc[mt][nt][r] + bsh[m]);
            }
    __syncthreads();

    unsigned int* dst = (unsigned int*)(c3 + ((size_t)(b * 64000 + s0)) * 96);
    for (int i = t; i < 12288; i += 256) {
        int row = i / 48, sg = i % 48;
        dst[i] = *(const unsigned int*)&st[row * 98 + sg * 2];
    }
}

// ---------------- per-(b,c) stats over f16 [b][s][96]: atomic partial sums ----------------
__global__ __launch_bounds__(192) void k_stats_sc(const _Float16* __restrict__ in,
                                                  float* __restrict__ raw) {   // [192][2]
    __shared__ float red_s[16][96], red_q[16][96];
    int bid = blockIdx.x;            // 100 blocks: b = bid/50, chunk of 1280 s
    int b = bid / 50, ch = bid % 50;
    int t = threadIdx.x;
    int sp = t / 12, cs = t % 12;
    const uint4* base = (const uint4*)(in + ((size_t)(b * 64000 + ch * 1280)) * 96);
    float s8[8], q8[8];
#pragma unroll
    for (int e = 0; e < 8; e++) { s8[e] = 0.f; q8[e] = 0.f; }
    for (int i = 0; i < 80; i++) {
        uint4 v = base[(sp + i * 16) * 12 + cs];
        half8 h = __builtin_bit_cast(half8, v);
#pragma unroll
        for (int e = 0; e < 8; e++) { float f = (float)h[e]; s8[e] += f; q8[e] += f * f; }
    }
#pragma unroll
    for (int e = 0; e < 8; e++) { red_s[sp][cs * 8 + e] = s8[e]; red_q[sp][cs * 8 + e] = q8[e]; }
    __syncthreads();
    if (t < 96) {
        float S = 0.f, Q = 0.f;
        for (int k = 0; k < 16; k++) { S += red_s[k][t]; Q += red_q[k][t]; }
        atomicAdd(&raw[(b * 96 + t) * 2], S);
        atomicAdd(&raw[(b * 96 + t) * 2 + 1], Q);
    }
}

// ---------------- 96x96 f16 MFMA GEMM with fused norm+gelu on B input ----------------
// MODE 0: out = W @ gelu(IN(in)) + bias (f16). MODE 1: out = x * sigmoid(same).
template <int MODE>
__global__ __launch_bounds__(256) void k_gemm96(const _Float16* __restrict__ in,
                                                const _Float16* __restrict__ w,   // [96][96]
                                                const float* __restrict__ bias,
                                                const float* __restrict__ raw,    // [192][2] sum/sumsq
                                                const float* __restrict__ xg,     // [b][c][s] f32 (MODE 1)
                                                _Float16* __restrict__ outp) {
    __shared__ _Float16 un[12544];   // union: W (9216) | out staging 128 x 98
    __shared__ float bias_s[96];
    __shared__ float2 sfl[96];
    int t = threadIdx.x, bid = blockIdx.x;
    int b = bid / 500, s0 = (bid % 500) * 128;
    for (int i = t; i < 1152; i += 256) ((uint4*)un)[i] = ((const uint4*)w)[i];
    if (t < 96) {
        bias_s[t] = bias[t];
        float S = raw[(b * 96 + t) * 2], Q = raw[(b * 96 + t) * 2 + 1];
        float mu = S * (1.f / 64000.f);
        float var = Q * (1.f / 64000.f) - mu * mu;
        sfl[t] = make_float2(mu, rsqrtf(var + 1e-5f));
    }
    __syncthreads();

    int ws = t >> 6, lane = t & 63;
    int n = lane & 31, kg = lane >> 5;
    int p = ws * 32 + n;
    const uint4* brow = (const uint4*)(in + ((size_t)(b * 64000 + s0 + p)) * 96);
    uint4 bf[6];
#pragma unroll
    for (int kc = 0; kc < 6; kc++) {
        uint4 v = brow[kc * 2 + kg];
        half8 h = __builtin_bit_cast(half8, v);
        _Float16 g[8];
#pragma unroll
        for (int e = 0; e < 8; e++) {
            int c = kc * 16 + kg * 8 + e;
            float2 sv = sfl[c];
            float u = ((float)h[e] - sv.x) * sv.y;
            g[e] = (_Float16)(0.5f * u * (1.f + erff(u * 0.70710678118654752f)));
        }
        bf[kc] = *(uint4*)g;
    }

    floatx16 acc[3];
#pragma unroll
    for (int mt = 0; mt < 3; mt++)
#pragma unroll
        for (int r = 0; r < 16; r++) acc[mt][r] = 0.f;
#pragma unroll
    for (int kc = 0; kc < 6; kc++) {
        half8 bfh = __builtin_bit_cast(half8, bf[kc]);
#pragma unroll
        for (int mt = 0; mt < 3; mt++) {
            uint4 au = *(const uint4*)&un[(mt * 32 + n) * 96 + kc * 16 + kg * 8];
            acc[mt] = __builtin_amdgcn_mfma_f32_32x32x16_f16(__builtin_bit_cast(half8, au), bfh, acc[mt], 0, 0, 0);
        }
    }
    __syncthreads();   // done reading W; un becomes output staging

#pragma unroll
    for (int mt = 0; mt < 3; mt++)
#pragma unroll
        for (int r = 0; r < 16; r++) {
            int m = mt * 32 + (r & 3) + 8 * (r >> 2) + 4 * kg;
            int sl = ws * 32 + n;
            float v = acc[mt][r] + bias_s[m];
            if (MODE == 1) {
                v = 1.f / (1.f + __expf(-v));
                v *= xg[((size_t)(b * 96 + m)) * 64000 + s0 + sl];
            }
            un[sl * 98 + m] = (_Float16)v;
        }
    __syncthreads();

    unsigned int* dst = (unsigned int*)(outp + ((size_t)(b * 64000 + s0)) * 96);
    for (int i = t; i < 6144; i += 256) {
        int row = i / 48, sg = i % 48;
        dst[i] = *(const unsigned int*)&un[row * 98 + sg * 2];
    }
}

// ---------------- qkv GEMM (ONCE): qA[b][s][288] f16, natural s-order ----------------
__global__ __launch_bounds__(256) void k_qkv(const _Float16* __restrict__ xt,
                                             const _Float16* __restrict__ wq,  // [288][96]
                                             const float* __restrict__ qb,
                                             _Float16* __restrict__ qA) {
    __shared__ _Float16 smem[27648];   // union: A (288x96) then epi (64 x 296)
    __shared__ float bias_s[288];
    int t = threadIdx.x;
    int bid = blockIdx.x;
    int b = bid / 500;
    int s0 = (bid % 500) * 128;

    for (int i = t; i < 3456; i += 256) ((uint4*)smem)[i] = ((const uint4*)wq)[i];
    for (int i = t; i < 288; i += 256) bias_s[i] = qb[i];
    __syncthreads();

    int ws = t >> 6, lane = t & 63;
    int n = lane & 31, kg = lane >> 5;
    int p = ws * 32 + n;

    const uint4* brow = (const uint4*)(xt + ((size_t)(b * 64000 + s0 + p)) * 96);
    uint4 bf[6];
#pragma unroll
    for (int kc = 0; kc < 6; kc++) bf[kc] = brow[kc * 2 + kg];

    floatx16 acc[9];
#pragma unroll
    for (int mt = 0; mt < 9; mt++)
#pragma unroll
        for (int r = 0; r < 16; r++) acc[mt][r] = 0.f;

#pragma unroll
    for (int kc = 0; kc < 6; kc++) {
        half8 bfh = __builtin_bit_cast(half8, bf[kc]);
#pragma unroll
        for (int mt = 0; mt < 9; mt++) {
            uint4 au = *(const uint4*)&smem[(mt * 32 + n) * 96 + kc * 16 + kg * 8];
            acc[mt] = __builtin_amdgcn_mfma_f32_32x32x16_f16(__builtin_bit_cast(half8, au), bfh, acc[mt], 0, 0, 0);
        }
    }

    const float scale = 0.20412414523193154f;
    for (int q = 0; q < 2; q++) {
        __syncthreads();
        if ((ws >> 1) == q) {
            int pl = (ws & 1) * 32 + n;
#pragma unroll
            for (int mt = 0; mt < 9; mt++)
#pragma unroll
                for (int g = 0; g < 4; g++) {
                    int m0 = mt * 32 + g * 8 + kg * 4;
                    _Float16 tm[4];
#pragma unroll
                    for (int j = 0; j < 4; j++) {
                        float v = acc[mt][g * 4 + j] + bias_s[m0 + j];
                        if (m0 + j < 96) v *= scale;
                        tm[j] = (_Float16)v;
                    }
                    *(uint2*)&smem[pl * 296 + m0] = *(uint2*)tm;
                }
        }
        __syncthreads();
        for (int idx = t; idx < 2304; idx += 256) {
            int pl = idx / 36, seg = idx % 36;
            int s = s0 + q * 64 + pl;
            uint4 v = *(const uint4*)&smem[pl * 296 + seg * 8];
            *(uint4*)&qA[((size_t)(b * 64000 + s)) * 288 + seg * 8] = v;
        }
    }
}

// ---------------- fused axial attention: softmax + PV, sum into osum[b][s][96] ----------------
template <int AXIS, bool ACC>
__global__ __launch_bounds__(320, 3) void k_attn(const _Float16* __restrict__ qA,
                                                 _Float16* __restrict__ osum) {
    __shared__ _Float16 kk[8352];     // k: [line][key][96]; then out staging [line][l][104]
    __shared__ _Float16 vT[7744];     // plane lh=line*4+head, stride 968: [hd][40 keys]
    int t = threadIdx.x;
    int bid = blockIdx.x;
    int b = bid / 800;
    int r0 = (bid % 800) * 2;

    auto smap = [&](int r, int l) -> int {
        if (AXIS == 0) return l * 1600 + r;
        else if (AXIS == 1) { int d = r / 40, w = r % 40; return d * 1600 + l * 40 + w; }
        else return r * 40 + l;
    };
    const uint4* src = (const uint4*)qA;
    for (int i = t; i < 960; i += 320) {
        int line = i / 480, key = (i % 480) / 12, seg = i % 12;
        int row = b * 64000 + smap(r0 + line, key);
        ((uint4*)kk)[i] = src[(size_t)row * 36 + 12 + seg];
    }
    for (int i = t; i < 960; i += 320) {
        int line = i / 480, key = (i % 480) / 12, seg = i % 12;
        int row = b * 64000 + smap(r0 + line, key);
        uint4 v = src[(size_t)row * 36 + 24 + seg];
        _Float16 tmp[8];
        *(uint4*)tmp = v;
#pragma unroll
        for (int e = 0; e < 8; e++) {
            int hdg = seg * 8 + e;
            vT[(line * 4 + hdg / 24) * 968 + (hdg % 24) * 40 + key] = tmp[e];
        }
    }

    int line = t / 160, head = (t % 160) / 40, ql = t % 40;
    int rr = r0 + line;
    unsigned int qu[12];
    {
        const uint4* qp = (const uint4*)(qA + ((size_t)(b * 64000 + smap(rr, ql))) * 288 + head * 24);
#pragma unroll
        for (int j = 0; j < 3; j++) *(uint4*)&qu[j * 4] = qp[j];
    }
    __syncthreads();

    float s[40];
    const uint4* kbase = (const uint4*)kk + line * 480 + head * 3;
#pragma unroll 4
    for (int key = 0; key < 40; key++) {
        unsigned int kku[12];
#pragma unroll
        for (int j = 0; j < 3; j++) *(uint4*)&kku[j * 4] = kbase[key * 12 + j];
        float a = 0.f;
#pragma unroll
        for (int i = 0; i < 12; i++) a = fdot2(kku[i], qu[i], a);
        s[key] = a;
    }

    float mx = -1e30f;
#pragma unroll
    for (int i = 0; i < 40; i++) mx = fmaxf(mx, s[i]);
    float sum = 0.f;
#pragma unroll
    for (int i = 0; i < 40; i++) { s[i] = __expf(s[i] - mx); sum += s[i]; }
    float inv = 1.f / sum;

    unsigned int pw[20];
#pragma unroll
    for (int i = 0; i < 20; i++) {
        half2 a = { (_Float16)(s[2 * i] * inv), (_Float16)(s[2 * i + 1] * inv) };
        pw[i] = __builtin_bit_cast(unsigned int, a);
    }

    __syncthreads();   // kk becomes output staging

    float o[24];
    const uint4* vbase = (const uint4*)vT + (line * 4 + head) * 121;
#pragma unroll 2
    for (int hd = 0; hd < 24; hd++) {
        unsigned int vv[20];
#pragma unroll
        for (int j = 0; j < 5; j++) *(uint4*)&vv[j * 4] = vbase[hd * 5 + j];
        float a = 0.f;
#pragma unroll
        for (int i = 0; i < 20; i++) a = fdot2(vv[i], pw[i], a);
        o[hd] = a;
    }

    {
        _Float16 tm[24];
#pragma unroll
        for (int j = 0; j < 24; j++) tm[j] = (_Float16)o[j];
        _Float16* dA = &kk[(line * 40 + ql) * 104 + head * 24];
#pragma unroll
        for (int j = 0; j < 3; j++) ((uint4*)dA)[j] = ((uint4*)tm)[j];
    }
    __syncthreads();

    uint4* dst = (uint4*)osum;
    for (int i = t; i < 960; i += 320) {
        int row = i / 12, seg = i % 12;
        int s2 = smap(r0 + row / 40, row % 40);
        size_t di = ((size_t)(b * 64000 + s2)) * 12 + seg;
        uint4 v = *(const uint4*)&kk[row * 104 + seg * 8];
        if (ACC) {
            half8 a = __builtin_bit_cast(half8, dst[di]);
            half8 c = __builtin_bit_cast(half8, v);
            dst[di] = __builtin_bit_cast(uint4, a + c);
        } else {
            dst[di] = v;
        }
    }
}

// ---------------- proj GEMM: out[b][c][s] = proj_w @ osum[b][s][96] + pb ----------------
__global__ __launch_bounds__(256) void k_proj(const _Float16* __restrict__ osum,
                                              const _Float16* __restrict__ wp,  // [96][96]
                                              const float* __restrict__ pb,
                                              float* __restrict__ out) {
    __shared__ _Float16 A[9216];
    __shared__ float bias_s[96];
    int t = threadIdx.x;
    int bid = blockIdx.x;
    int b = bid / 500;
    int s0 = (bid % 500) * 128;
    for (int i = t; i < 1152; i += 256) ((uint4*)A)[i] = ((const uint4*)wp)[i];
    if (t < 96) bias_s[t] = pb[t];
    __syncthreads();

    int ws = t >> 6, lane = t & 63;
    int n = lane & 31, kg = lane >> 5;
    int s = s0 + ws * 32 + n;

    const uint4* brow = (const uint4*)(osum + ((size_t)(b * 64000 + s)) * 96);
    uint4 bf[6];
#pragma unroll
    for (int kc = 0; kc < 6; kc++) bf[kc] = brow[kc * 2 + kg];

    floatx16 acc[3];
#pragma unroll
    for (int mt = 0; mt < 3; mt++)
#pragma unroll
        for (int r = 0; r < 16; r++) acc[mt][r] = 0.f;

#pragma unroll
    for (int kc = 0; kc < 6; kc++) {
        half8 bfh = __builtin_bit_cast(half8, bf[kc]);
#pragma unroll
        for (int mt = 0; mt < 3; mt++) {
            uint4 au = *(const uint4*)&A[(mt * 32 + n) * 96 + kc * 16 + kg * 8];
            acc[mt] = __builtin_amdgcn_mfma_f32_32x32x16_f16(__builtin_bit_cast(half8, au), bfh, acc[mt], 0, 0, 0);
        }
    }

#pragma unroll
    for (int mt = 0; mt < 3; mt++)
#pragma unroll
        for (int r = 0; r < 16; r++) {
            int m = mt * 32 + (r & 3) + 8 * (r >> 2) + 4 * kg;
            out[((size_t)(b * 96 + m)) * 64000 + s] = acc[mt][r] + bias_s[m];
        }
}

extern "C" void kernel_launch(void* const* d_in, const int* in_sizes, int n_in,
                              void* d_out, int out_size, void* d_ws, size_t ws_size,
                              hipStream_t stream) {
    const float* x      = (const float*)d_in[0];
    const float* pos    = (const float*)d_in[1];
    const float* qkv_w  = (const float*)d_in[2];
    const float* qkv_b  = (const float*)d_in[3];
    const float* lp1_w  = (const float*)d_in[4];
    const float* lp1_b  = (const float*)d_in[5];
    const float* lp2_w  = (const float*)d_in[6];
    const float* lp2_b  = (const float*)d_in[7];
    const float* mod1_w = (const float*)d_in[8];
    const float* mod1_b = (const float*)d_in[9];
    const float* mod2_w = (const float*)d_in[10];
    const float* mod2_b = (const float*)d_in[11];
    // d_in[12..16]: pa_w, pa_b, R6_d, R6_h, R6_w — provably no-ops (see header)
    const float* proj_w = (const float*)d_in[17];
    const float* proj_b = (const float*)d_in[18];
    float* out = (float*)d_out;
    float* ws = (float*)d_ws;

    _Float16* bufA = (_Float16*)ws;                        // 12.288M f16: c3 -> xm
    _Float16* bufB = (_Float16*)(ws + 6144000);            // 12.288M f16: C2 -> osum
    _Float16* qA   = (_Float16*)(ws + 12288000);           // 36.864M f16
    _Float16* in_t = qA;                                   // pos f16 [s][c], dead before qkv
    _Float16* wf   = (_Float16*)(ws + 30720000);           // 248,832 f16 (fragment order)
    _Float16* wq   = (_Float16*)(ws + 30844416);           // 27,648 f16
    _Float16* wpj  = (_Float16*)(ws + 30858240);           // 9,216 f16
    _Float16* wfold= (_Float16*)(ws + 30862848);           // 9,216 f16
    _Float16* wm2  = (_Float16*)(ws + 30867456);           // 9,216 f16
    float* bfold   = ws + 30872064;                        // 96 f32
    float* raw     = ws + 30872160;                        // 768 f32 (raw0 | raw1)
    float* raw0 = raw, *raw1 = raw + 384;

    k_prep<<<1192, 256, 0, stream>>>(lp1_w, lp2_w, lp2_b, mod1_w, mod1_b, mod2_w,
                                     qkv_w, proj_w, wf, wfold, wm2, wq, wpj, bfold, raw);
    k_cvt_in<<<2000, 256, 0, stream>>>(pos, in_t);

    // c3 = conv3(pos)  [f16 [b][s][96]]
    k_conv3_v3<<<500, 256, 0, stream>>>(in_t, wf, lp1_b, bufA);
    // C2 = W' @ gelu(IN(c3)) + b'   (ng fused into B path)
    k_stats_sc<<<100, 192, 0, stream>>>(bufA, raw0);
    k_gemm96<0><<<1000, 256, 0, stream>>>(bufA, wfold, bfold, raw0, nullptr, bufB);
    // xm = x * sigmoid(mod2 @ gelu(IN(C2)) + b)
    k_stats_sc<<<100, 192, 0, stream>>>(bufB, raw1);
    k_gemm96<1><<<1000, 256, 0, stream>>>(bufB, wm2, mod2_b, raw1, x, bufA);

    // qkv ONCE (s-order); qA overwrites in_t (dead)
    k_qkv<<<1000, 256, 0, stream>>>(bufA, wq, qkv_b, qA);
    // attention: axis 2 writes osum (contiguous), axes 0/1 accumulate (192B-row RMW)
    k_attn<2, false><<<1600, 320, 0, stream>>>(qA, bufB);
    k_attn<0, true ><<<1600, 320, 0, stream>>>(qA, bufB);
    k_attn<1, true ><<<1600, 320, 0, stream>>>(qA, bufB);

    // out = proj(osum)
    k_proj<<<1000, 256, 0, stream>>>(bufB, wpj, proj_b, out);
}